// Round 7
// baseline (3859.212 us; speedup 1.0000x reference)
//
#include <hip/hip_runtime.h>
#include <math.h>

// RNG: layout 4 = partitionable XOR: bits[i] = o0^o1 of threefry((0,1),(0,i)).
// Evidence: R4/R6 absmax 5.171875 == ONE boundary swap (max|ref|=5.66); other layouts
// give 7.8-9.5 (wholesale). Core KAT-verified on HW (R5). This round: f64 accumulation
// through the whole conf-feeding pipeline (f32 storage) to kill the boundary flip.

#define BB 16
#define NN 3136
#define CC 256
#define NHEADS 4
#define DH 64
#define MLPH 1024
#define NGRID 196
#define NREST 2940
#define KADA 588
#define HW 56
#define BCH 2

__device__ __forceinline__ int inv_order(int p) {
  int r = p / HW, c = p % HW;
  if ((r & 3) == 2 && (c & 3) == 2) return (r >> 2) * 14 + (c >> 2);
  int g = ((r + 1) >> 2) * 14 + (((r & 3) == 2) ? ((c + 1) >> 2) : 0);
  return NGRID + p - g;
}

__device__ __forceinline__ double gelu_d(double v) {
  return 0.5 * v * (1.0 + erf(v * 0.70710678118654752440));
}

__device__ __forceinline__ void tf2x32k(unsigned k0, unsigned k1, unsigned x0, unsigned x1,
                                        unsigned& o0, unsigned& o1) {
  unsigned ks[3] = {k0, k1, k0 ^ k1 ^ 0x1BD11BDAu};
  x0 += ks[0]; x1 += ks[1];
  const int rot[2][4] = {{13,15,26,6},{17,29,16,24}};
  #pragma unroll
  for (int i = 0; i < 5; ++i) {
    #pragma unroll
    for (int j = 0; j < 4; ++j) {
      int rr = rot[i & 1][j];
      x0 += x1;
      x1 = (x1 << rr) | (x1 >> (32 - rr));
      x1 ^= x0;
    }
    x0 += ks[(i + 1) % 3];
    x1 += ks[(i + 2) % 3] + (unsigned)(i + 1);
  }
  o0 = x0; o1 = x1;
}

__device__ bool tf_kat() {
  unsigned a, b;
  tf2x32k(0u, 0u, 0u, 0u, a, b);
  if (a != 0x6b200159u || b != 0x99ba4efeu) return false;
  tf2x32k(0xffffffffu, 0xffffffffu, 0xffffffffu, 0xffffffffu, a, b);
  if (a != 0x1cb996fcu || b != 0xbb002be7u) return false;
  tf2x32k(0x13198a2eu, 0x03707344u, 0x243f6a88u, 0x85a308d3u, a, b);
  if (a != 0xc4923a9cu || b != 0x483df7a0u) return false;
  return true;
}

// f32 uniform value (bit-exact jax draw), gumbel computed in f64 (np referee math)
__device__ __forceinline__ double gumbel_d(int f) {
  unsigned o0, o1;
  tf2x32k(0u, 1u, 0u, (unsigned)f, o0, o1);
  unsigned bits = o0 ^ o1;
  float u = __uint_as_float((bits >> 9) | 0x3f800000u) - 1.0f;
  double ud = (double)u;
  return -log(-log(ud + 1e-6) + 1e-6);
}

// ---------- kernels ----------
__global__ void k_order(int* __restrict__ ord) {
  int p = blockIdx.x * 256 + threadIdx.x;
  if (p < NN) ord[inv_order(p)] = p;
}

// reorder + LN1 (f64 stats)
__global__ __launch_bounds__(256) void k_ln1(const float* __restrict__ x,
    const float* __restrict__ g, const float* __restrict__ b2,
    float* __restrict__ x_r, float* __restrict__ xn) {
  int b = blockIdx.x / NN, p = blockIdx.x % NN;
  int t = threadIdx.x;
  __shared__ double red[256];
  float v = x[((size_t)b*NN + p)*CC + t];
  double vd = (double)v;
  red[t] = vd; __syncthreads();
  for (int s = 128; s > 0; s >>= 1) { if (t < s) red[t] += red[t+s]; __syncthreads(); }
  double m = red[0] * (1.0/CC);
  __syncthreads();
  double d = vd - m;
  red[t] = d*d; __syncthreads();
  for (int s = 128; s > 0; s >>= 1) { if (t < s) red[t] += red[t+s]; __syncthreads(); }
  double var = red[0] * (1.0/CC);
  double o = d * (1.0 / sqrt(var + 1e-5)) * (double)g[t] + (double)b2[t];
  int n = inv_order(p);
  size_t dst = ((size_t)b*NN + n)*CC + t;
  x_r[dst] = v;
  xn[dst] = (float)o;
}

__global__ __launch_bounds__(256) void k_ln2(const float* __restrict__ xin,
    const float* __restrict__ g, const float* __restrict__ b2, float* __restrict__ xo) {
  int row = blockIdx.x;
  int t = threadIdx.x;
  __shared__ double red[256];
  double v = (double)xin[(size_t)row*CC + t];
  red[t] = v; __syncthreads();
  for (int s = 128; s > 0; s >>= 1) { if (t < s) red[t] += red[t+s]; __syncthreads(); }
  double m = red[0] * (1.0/CC);
  __syncthreads();
  double d = v - m;
  red[t] = d*d; __syncthreads();
  for (int s = 128; s > 0; s >>= 1) { if (t < s) red[t] += red[t+s]; __syncthreads(); }
  double var = red[0] * (1.0/CC);
  xo[(size_t)row*CC + t] = (float)(d * (1.0 / sqrt(var + 1e-5)) * (double)g[t] + (double)b2[t]);
}

// 8x8 avg-pool (token-raster) + 1x1 conv, all f64 accum
__global__ __launch_bounds__(256) void k_sr(const float* __restrict__ xn,
    const float* __restrict__ sr_w, const float* __restrict__ sr_b, float* __restrict__ srout) {
  int b = blockIdx.x / 49, cell = blockIdx.x % 49;
  int p1 = cell / 7, p2 = cell % 7;
  int t = threadIdx.x;
  __shared__ double pl[256];
  double s = 0.0;
  #pragma unroll
  for (int i = 0; i < 8; ++i)
    #pragma unroll
    for (int j = 0; j < 8; ++j) {
      int n = (p1*8 + i)*HW + (p2*8 + j);
      s += (double)xn[((size_t)b*NN + n)*CC + t];
    }
  pl[t] = s * (1.0/64.0);
  __syncthreads();
  double acc = (double)sr_b[t];
  for (int i = 0; i < CC; ++i) acc += pl[i] * (double)sr_w[t*CC + i];
  srout[((size_t)b*49 + cell)*CC + t] = (float)acc;
}

// LN + gelu + kv projection, f64
__global__ __launch_bounds__(256) void k_kv(const float* __restrict__ srout,
    const float* __restrict__ g, const float* __restrict__ b2,
    const float* __restrict__ wkv, float* __restrict__ kb, float* __restrict__ vb) {
  int b = blockIdx.x / 49, m = blockIdx.x % 49;
  int t = threadIdx.x;
  __shared__ double red[256];
  __shared__ double tl[256];
  double v = (double)srout[((size_t)b*49 + m)*CC + t];
  red[t] = v; __syncthreads();
  for (int s = 128; s > 0; s >>= 1) { if (t < s) red[t] += red[t+s]; __syncthreads(); }
  double mean = red[0] * (1.0/CC);
  __syncthreads();
  double d = v - mean;
  red[t] = d*d; __syncthreads();
  for (int s = 128; s > 0; s >>= 1) { if (t < s) red[t] += red[t+s]; __syncthreads(); }
  double var = red[0] * (1.0/CC);
  double o = d * (1.0 / sqrt(var + 1e-5)) * (double)g[t] + (double)b2[t];
  tl[t] = gelu_d(o);
  __syncthreads();
  #pragma unroll
  for (int rep = 0; rep < 2; ++rep) {
    int j = t + rep*256;
    double acc = 0.0;
    for (int i = 0; i < CC; ++i) acc += tl[i] * (double)wkv[(size_t)i*512 + j];
    int h = (j >> 6) & 3, dd = j & 63;
    float* dst = (j >> 8) ? vb : kb;
    dst[(((size_t)b*NHEADS + h)*49 + m)*DH + dd] = (float)acc;
  }
}

// GEMM, f32 in/out, f64 accumulate; BM=BN=64, BK=16, 256 thr, 4x4 micro
template<int BIAS, int RELU, int RESID>
__global__ __launch_bounds__(256) void k_gemm64(const float* __restrict__ A,
    const float* __restrict__ Bw, const float* __restrict__ bias,
    const float* resid, float* Co, int M, int N, int K) {
  __shared__ __align__(16) float As[16][68];
  __shared__ __align__(16) float Bs[16][68];
  int tid = threadIdx.x;
  int n0 = blockIdx.x * 64, m0 = blockIdx.y * 64;
  int tx = tid & 15, ty = tid >> 4;
  int aM = tid >> 2, aK = (tid & 3) * 4;
  int bK = tid >> 4, bN = (tid & 15) * 4;
  double acc[4][4] = {};
  for (int k0 = 0; k0 < K; k0 += 16) {
    float4 a4 = *(const float4*)&A[(size_t)(m0 + aM) * K + k0 + aK];
    As[aK+0][aM] = a4.x; As[aK+1][aM] = a4.y; As[aK+2][aM] = a4.z; As[aK+3][aM] = a4.w;
    float4 b4 = *(const float4*)&Bw[(size_t)(k0 + bK) * N + n0 + bN];
    *(float4*)&Bs[bK][bN] = b4;
    __syncthreads();
    #pragma unroll
    for (int k = 0; k < 16; ++k) {
      double av[4], bv[4];
      #pragma unroll
      for (int r = 0; r < 4; ++r) av[r] = (double)As[k][ty*4 + r];
      #pragma unroll
      for (int c = 0; c < 4; ++c) bv[c] = (double)Bs[k][tx*4 + c];
      #pragma unroll
      for (int r = 0; r < 4; ++r)
        #pragma unroll
        for (int c = 0; c < 4; ++c)
          acc[r][c] = fma(av[r], bv[c], acc[r][c]);
    }
    __syncthreads();
  }
  #pragma unroll
  for (int r = 0; r < 4; ++r) {
    size_t off = (size_t)(m0 + ty*4 + r) * N + n0 + tx*4;
    #pragma unroll
    for (int c = 0; c < 4; ++c) {
      double v = acc[r][c];
      if (BIAS)  v += (double)bias[n0 + tx*4 + c];
      if (RESID) v += (double)resid[off + c];
      if (RELU)  v = fmax(v, 0.0);
      Co[off + c] = (float)v;
    }
  }
}

// attention: logits f64, softmax f64, PV f64
__global__ __launch_bounds__(64) void k_attn(float* __restrict__ q,
    const float* __restrict__ kb, const float* __restrict__ vb) {
  int b = blockIdx.x / NN, n = blockIdx.x % NN;
  int t = threadIdx.x;
  __shared__ float qs[256];
  __shared__ double lg[4][52];
  __shared__ double sinv[4];
  float* qrow = q + ((size_t)b*NN + n)*CC;
  #pragma unroll
  for (int i = 0; i < 4; ++i) qs[t + i*64] = qrow[t + i*64];
  __syncthreads();
  for (int li = t; li < 196; li += 64) {
    int h = li / 49, m = li % 49;
    const float* kr = kb + (((size_t)b*NHEADS + h)*49 + m)*DH;
    const float* qh = qs + h*DH;
    double acc = 0.0;
    #pragma unroll 16
    for (int d = 0; d < DH; ++d) acc = fma((double)qh[d], (double)kr[d], acc);
    lg[h][m] = acc * 0.125;
  }
  __syncthreads();
  if (t < 4) {
    double mx = -1e300;
    for (int j = 0; j < 49; ++j) mx = fmax(mx, lg[t][j]);
    double s = 0.0;
    for (int j = 0; j < 49; ++j) { double e = exp(lg[t][j] - mx); lg[t][j] = e; s += e; }
    sinv[t] = 1.0 / s;
  }
  __syncthreads();
  #pragma unroll
  for (int h = 0; h < 4; ++h) {
    const float* vr = vb + (((size_t)b*NHEADS + h)*49)*DH + t;
    double acc = 0.0;
    for (int m = 0; m < 49; ++m) acc = fma(lg[h][m], (double)vr[m*DH], acc);
    qrow[h*64 + t] = (float)(acc * sinv[h]);
  }
}

// depthwise 3x3 + bias + gelu, f64
__global__ __launch_bounds__(256) void k_dw(const float* __restrict__ hb,
    const float* __restrict__ w, const float* __restrict__ bias, float* __restrict__ h2) {
  int bl = blockIdx.x / NN, n = blockIdx.x % NN;
  int r = n / HW, c = n % HW;
  int t = threadIdx.x;
  const size_t base = (size_t)bl * NN;
  #pragma unroll
  for (int it = 0; it < 4; ++it) {
    int mc = t + it*256;
    double acc = (double)bias[mc];
    #pragma unroll
    for (int ky = 0; ky < 3; ++ky) {
      int rr = r + ky - 1;
      if (rr < 0 || rr >= HW) continue;
      #pragma unroll
      for (int kx = 0; kx < 3; ++kx) {
        int cc2 = c + kx - 1;
        if (cc2 < 0 || cc2 >= HW) continue;
        acc = fma((double)w[mc*9 + ky*3 + kx], (double)hb[(base + rr*HW + cc2)*MLPH + mc], acc);
      }
    }
    h2[(base + n)*MLPH + mc] = (float)gelu_d(acc);
  }
}

// conf f64 + gumbel f64 + exact top-k
__global__ __launch_bounds__(1024) void k_topk(const float* __restrict__ x3,
    const float* __restrict__ cw, const float* __restrict__ cb, int* __restrict__ sel) {
  int b = blockIdx.x, t = threadIdx.x;
  __shared__ float wsm[256];
  __shared__ double sc[NREST];
  if (t < 256) wsm[t] = cw[t];
  __syncthreads();
  for (int i = t; i < NREST; i += 1024) {
    const float* xr = x3 + ((size_t)b*NN + NGRID + i)*CC;
    double acc = (double)cb[0];
    #pragma unroll 8
    for (int c = 0; c < CC; ++c) acc += (double)xr[c] * (double)wsm[c];
    sc[i] = acc + gumbel_d(b*NREST + i);
  }
  __syncthreads();
  for (int i = t; i < NREST; i += 1024) {
    double si = sc[i];
    int rank = 0;
    for (int j = 0; j < NREST; ++j) {
      double sj = sc[j];
      rank += (int)((sj > si) | ((sj == si) & (j < i)));
    }
    if (rank < KADA) sel[b*KADA + rank] = NGRID + i;
  }
}

// token2map == 2x2 avg pool
__global__ __launch_bounds__(256) void k_t2m(const float* __restrict__ x3, float* __restrict__ fm) {
  int b = blockIdx.x / 784, pix = blockIdx.x % 784;
  int py = pix / 28, px = pix % 28;
  int t = threadIdx.x;
  float s = 0.f;
  #pragma unroll
  for (int dy = 0; dy < 2; ++dy)
    #pragma unroll
    for (int dx = 0; dx < 2; ++dx) {
      int p = (2*py + dy)*HW + 2*px + dx;
      s += x3[((size_t)b*NN + inv_order(p))*CC + t];
    }
  fm[((size_t)b*784 + pix)*CC + t] = s * (1.0f / 4.000001f);
}

// gather + bilinear sample + output (+KAT sentinel)
__global__ __launch_bounds__(256) void k_out(const float* __restrict__ x3,
    const float* __restrict__ fm, const int* __restrict__ sel,
    const int* __restrict__ ord, float* __restrict__ out) {
  int b = blockIdx.x / 784, slot = blockIdx.x % 784;
  int t = threadIdx.x;
  int n = (slot < NGRID) ? slot : sel[b*KADA + slot - NGRID];
  int p = ord[n];
  int r = p / HW, c = p % HW;
  int ix0 = (c - 1) >> 1;
  int iy0 = (r - 1) >> 1;
  float wx = (c & 1) ? 0.25f : 0.75f;
  float wy = (r & 1) ? 0.25f : 0.75f;
  const float* fb = fm + (size_t)b*784*CC + t;
  float v = 0.f;
  float w00 = (1.f-wx)*(1.f-wy), w01 = wx*(1.f-wy), w10 = (1.f-wx)*wy, w11 = wx*wy;
  if (ix0 >= 0   && iy0 >= 0)   v += w00 * fb[(iy0*28 + ix0)*CC];
  if (ix0+1 < 28 && iy0 >= 0)   v += w01 * fb[(iy0*28 + ix0+1)*CC];
  if (ix0 >= 0   && iy0+1 < 28) v += w10 * fb[((iy0+1)*28 + ix0)*CC];
  if (ix0+1 < 28 && iy0+1 < 28) v += w11 * fb[((iy0+1)*28 + ix0+1)*CC];
  float res = x3[((size_t)b*NN + n)*CC + t] + v;
  if (blockIdx.x == 0 && t == 0) {
    if (!tf_kat()) res += 1000.0f;
  }
  out[((size_t)b*784 + slot)*CC + t] = res;
}

// ---------- launch ----------
extern "C" void kernel_launch(void* const* d_in, const int* in_sizes, int n_in,
                              void* d_out, int out_size, void* d_ws, size_t ws_size,
                              hipStream_t stream) {
  const float* x      = (const float*)d_in[0];
  const float* ln1_g  = (const float*)d_in[1];
  const float* ln1_b  = (const float*)d_in[2];
  const float* wq     = (const float*)d_in[3];
  const float* wkv    = (const float*)d_in[4];
  const float* wproj  = (const float*)d_in[5];
  const float* bproj  = (const float*)d_in[6];
  const float* sr_w   = (const float*)d_in[7];
  const float* sr_b   = (const float*)d_in[8];
  const float* srn_g  = (const float*)d_in[9];
  const float* srn_b  = (const float*)d_in[10];
  const float* ln2_g  = (const float*)d_in[11];
  const float* ln2_b  = (const float*)d_in[12];
  const float* fc1_w  = (const float*)d_in[13];
  const float* fc1_b  = (const float*)d_in[14];
  const float* dw_w   = (const float*)d_in[15];
  const float* dw_b   = (const float*)d_in[16];
  const float* fc2_w  = (const float*)d_in[17];
  const float* fc2_b  = (const float*)d_in[18];
  const float* conf_w = (const float*)d_in[19];
  const float* conf_b = (const float*)d_in[20];
  float* out = (float*)d_out;

  float* ws = (float*)d_ws;
  const size_t SZ_XN = (size_t)BB*NN*CC;
  const size_t SZ_H  = (size_t)BCH*NN*MLPH;
  float* x_r   = ws;
  float* xn    = x_r + SZ_XN;
  float* qbuf  = xn + SZ_XN;
  float* hb    = qbuf + SZ_XN;
  float* h2b   = hb + SZ_H;
  float* srout = h2b + SZ_H;
  float* kb    = srout + (size_t)BB*49*CC;
  float* vb    = kb + (size_t)BB*NHEADS*49*DH;
  float* fm    = vb + (size_t)BB*NHEADS*49*DH;
  int*   sel   = (int*)(fm + (size_t)BB*784*CC);
  int*   ord   = sel + BB*KADA;

  k_order<<<(NN+255)/256, 256, 0, stream>>>(ord);
  k_ln1<<<BB*NN, 256, 0, stream>>>(x, ln1_g, ln1_b, x_r, xn);
  k_sr<<<BB*49, 256, 0, stream>>>(xn, sr_w, sr_b, srout);
  k_kv<<<BB*49, 256, 0, stream>>>(srout, srn_g, srn_b, wkv, kb, vb);
  k_gemm64<0,0,0><<<dim3(CC/64, BB*NN/64), 256, 0, stream>>>(xn, wq, nullptr, nullptr, qbuf, BB*NN, CC, CC);
  k_attn<<<BB*NN, 64, 0, stream>>>(qbuf, kb, vb);
  k_gemm64<1,0,1><<<dim3(CC/64, BB*NN/64), 256, 0, stream>>>(qbuf, wproj, bproj, x_r, x_r, BB*NN, CC, CC);
  k_ln2<<<BB*NN, 256, 0, stream>>>(x_r, ln2_g, ln2_b, xn);
  for (int bc = 0; bc < BB/BCH; ++bc) {
    const size_t ro = (size_t)bc * BCH * NN;
    k_gemm64<1,1,0><<<dim3(MLPH/64, BCH*NN/64), 256, 0, stream>>>(xn + ro*CC, fc1_w, fc1_b, nullptr, hb, BCH*NN, MLPH, CC);
    k_dw<<<BCH*NN, 256, 0, stream>>>(hb, dw_w, dw_b, h2b);
    k_gemm64<1,0,1><<<dim3(CC/64, BCH*NN/64), 256, 0, stream>>>(h2b, fc2_w, fc2_b, x_r + ro*CC, x_r + ro*CC, BCH*NN, CC, MLPH);
  }
  k_topk<<<BB, 1024, 0, stream>>>(x_r, conf_w, conf_b, sel);
  k_t2m<<<BB*784, 256, 0, stream>>>(x_r, fm);
  k_out<<<BB*784, 256, 0, stream>>>(x_r, fm, sel, ord, out);
}

// Round 8
// 3589.512 us; speedup vs baseline: 1.0751x; 1.0751x over previous
//
#include <hip/hip_runtime.h>
#include <math.h>

// RNG: partitionable XOR layout: bits[i] = o0^o1 of threefry((0,1),(0,i)). KAT-verified (R5).
// Precision: f32 storage + f64 accumulation everywhere (R7 PASS, absmax 0.0156).
// R4 (all-f32) flipped ONE top-k boundary -> do NOT degrade accumulate precision.

#define BB 16
#define NN 3136
#define CC 256
#define NHEADS 4
#define DH 64
#define MLPH 1024
#define NGRID 196
#define NREST 2940
#define KADA 588
#define HW 56
#define BCH 2

__device__ __forceinline__ int inv_order(int p) {
  int r = p / HW, c = p % HW;
  if ((r & 3) == 2 && (c & 3) == 2) return (r >> 2) * 14 + (c >> 2);
  int g = ((r + 1) >> 2) * 14 + (((r & 3) == 2) ? ((c + 1) >> 2) : 0);
  return NGRID + p - g;
}

__device__ __forceinline__ double gelu_d(double v) {
  return 0.5 * v * (1.0 + erf(v * 0.70710678118654752440));
}

__device__ __forceinline__ void tf2x32k(unsigned k0, unsigned k1, unsigned x0, unsigned x1,
                                        unsigned& o0, unsigned& o1) {
  unsigned ks[3] = {k0, k1, k0 ^ k1 ^ 0x1BD11BDAu};
  x0 += ks[0]; x1 += ks[1];
  const int rot[2][4] = {{13,15,26,6},{17,29,16,24}};
  #pragma unroll
  for (int i = 0; i < 5; ++i) {
    #pragma unroll
    for (int j = 0; j < 4; ++j) {
      int rr = rot[i & 1][j];
      x0 += x1;
      x1 = (x1 << rr) | (x1 >> (32 - rr));
      x1 ^= x0;
    }
    x0 += ks[(i + 1) % 3];
    x1 += ks[(i + 2) % 3] + (unsigned)(i + 1);
  }
  o0 = x0; o1 = x1;
}

__device__ bool tf_kat() {
  unsigned a, b;
  tf2x32k(0u, 0u, 0u, 0u, a, b);
  if (a != 0x6b200159u || b != 0x99ba4efeu) return false;
  tf2x32k(0xffffffffu, 0xffffffffu, 0xffffffffu, 0xffffffffu, a, b);
  if (a != 0x1cb996fcu || b != 0xbb002be7u) return false;
  tf2x32k(0x13198a2eu, 0x03707344u, 0x243f6a88u, 0x85a308d3u, a, b);
  if (a != 0xc4923a9cu || b != 0x483df7a0u) return false;
  return true;
}

__device__ __forceinline__ double gumbel_d(int f) {
  unsigned o0, o1;
  tf2x32k(0u, 1u, 0u, (unsigned)f, o0, o1);
  unsigned bits = o0 ^ o1;
  float u = __uint_as_float((bits >> 9) | 0x3f800000u) - 1.0f;
  double ud = (double)u;
  return -log(-log(ud + 1e-6) + 1e-6);
}

// ---------- kernels ----------
__global__ void k_order(int* __restrict__ ord) {
  int p = blockIdx.x * 256 + threadIdx.x;
  if (p < NN) ord[inv_order(p)] = p;
}

// reorder + LN1 (f64 stats via wave shuffle)
__global__ __launch_bounds__(256) void k_ln1(const float* __restrict__ x,
    const float* __restrict__ g, const float* __restrict__ b2,
    float* __restrict__ x_r, float* __restrict__ xn) {
  int b = blockIdx.x / NN, p = blockIdx.x % NN;
  int t = threadIdx.x;
  __shared__ double la[4], lb[4];
  float v = x[((size_t)b*NN + p)*CC + t];
  double vd = (double)v;
  double s = vd;
  #pragma unroll
  for (int o = 32; o; o >>= 1) s += __shfl_xor(s, o, 64);
  if ((t & 63) == 0) la[t >> 6] = s;
  __syncthreads();
  double m = (la[0] + la[1] + la[2] + la[3]) * (1.0/CC);
  double d = vd - m;
  s = d * d;
  #pragma unroll
  for (int o = 32; o; o >>= 1) s += __shfl_xor(s, o, 64);
  if ((t & 63) == 0) lb[t >> 6] = s;
  __syncthreads();
  double var = (lb[0] + lb[1] + lb[2] + lb[3]) * (1.0/CC);
  double o2 = d * (1.0 / sqrt(var + 1e-5)) * (double)g[t] + (double)b2[t];
  int n = inv_order(p);
  size_t dst = ((size_t)b*NN + n)*CC + t;
  x_r[dst] = v;
  xn[dst] = (float)o2;
}

__global__ __launch_bounds__(256) void k_ln2(const float* __restrict__ xin,
    const float* __restrict__ g, const float* __restrict__ b2, float* __restrict__ xo) {
  int row = blockIdx.x;
  int t = threadIdx.x;
  __shared__ double la[4], lb[4];
  double v = (double)xin[(size_t)row*CC + t];
  double s = v;
  #pragma unroll
  for (int o = 32; o; o >>= 1) s += __shfl_xor(s, o, 64);
  if ((t & 63) == 0) la[t >> 6] = s;
  __syncthreads();
  double m = (la[0] + la[1] + la[2] + la[3]) * (1.0/CC);
  double d = v - m;
  s = d * d;
  #pragma unroll
  for (int o = 32; o; o >>= 1) s += __shfl_xor(s, o, 64);
  if ((t & 63) == 0) lb[t >> 6] = s;
  __syncthreads();
  double var = (lb[0] + lb[1] + lb[2] + lb[3]) * (1.0/CC);
  xo[(size_t)row*CC + t] = (float)(d * (1.0 / sqrt(var + 1e-5)) * (double)g[t] + (double)b2[t]);
}

// 8x8 avg-pool + 1x1 conv, f64 accum
__global__ __launch_bounds__(256) void k_sr(const float* __restrict__ xn,
    const float* __restrict__ sr_w, const float* __restrict__ sr_b, float* __restrict__ srout) {
  int b = blockIdx.x / 49, cell = blockIdx.x % 49;
  int p1 = cell / 7, p2 = cell % 7;
  int t = threadIdx.x;
  __shared__ double pl[256];
  double s = 0.0;
  #pragma unroll
  for (int i = 0; i < 8; ++i)
    #pragma unroll
    for (int j = 0; j < 8; ++j) {
      int n = (p1*8 + i)*HW + (p2*8 + j);
      s += (double)xn[((size_t)b*NN + n)*CC + t];
    }
  pl[t] = s * (1.0/64.0);
  __syncthreads();
  double acc = (double)sr_b[t];
  for (int i = 0; i < CC; ++i) acc += pl[i] * (double)sr_w[t*CC + i];
  srout[((size_t)b*49 + cell)*CC + t] = (float)acc;
}

// LN + gelu + kv projection, f64
__global__ __launch_bounds__(256) void k_kv(const float* __restrict__ srout,
    const float* __restrict__ g, const float* __restrict__ b2,
    const float* __restrict__ wkv, float* __restrict__ kb, float* __restrict__ vb) {
  int b = blockIdx.x / 49, m = blockIdx.x % 49;
  int t = threadIdx.x;
  __shared__ double la[4], lb[4];
  __shared__ double tl[256];
  double v = (double)srout[((size_t)b*49 + m)*CC + t];
  double s = v;
  #pragma unroll
  for (int o = 32; o; o >>= 1) s += __shfl_xor(s, o, 64);
  if ((t & 63) == 0) la[t >> 6] = s;
  __syncthreads();
  double mean = (la[0] + la[1] + la[2] + la[3]) * (1.0/CC);
  double d = v - mean;
  s = d * d;
  #pragma unroll
  for (int o = 32; o; o >>= 1) s += __shfl_xor(s, o, 64);
  if ((t & 63) == 0) lb[t >> 6] = s;
  __syncthreads();
  double var = (lb[0] + lb[1] + lb[2] + lb[3]) * (1.0/CC);
  double o2 = d * (1.0 / sqrt(var + 1e-5)) * (double)g[t] + (double)b2[t];
  tl[t] = gelu_d(o2);
  __syncthreads();
  #pragma unroll
  for (int rep = 0; rep < 2; ++rep) {
    int j = t + rep*256;
    double acc = 0.0;
    for (int i = 0; i < CC; ++i) acc += tl[i] * (double)wkv[(size_t)i*512 + j];
    int h = (j >> 6) & 3, dd = j & 63;
    float* dst = (j >> 8) ? vb : kb;
    dst[(((size_t)b*NHEADS + h)*49 + m)*DH + dd] = (float)acc;
  }
}

// GEMM A: BM=128, BN=64, BK=16, 256 thr, 8x4 f64 micro. M%128==0, N%64==0, K%16==0.
template<int BIAS, int RELU, int RESID>
__global__ __launch_bounds__(256) void k_gemmA(const float* __restrict__ A,
    const float* __restrict__ Bw, const float* __restrict__ bias,
    const float* resid, float* Co, int M, int N, int K) {
  __shared__ __align__(16) float As[16][132];
  __shared__ __align__(16) float Bs[16][68];
  int tid = threadIdx.x;
  int n0 = blockIdx.x * 64, m0 = blockIdx.y * 128;
  int tx = tid & 15, ty = tid >> 4;
  int aM = tid >> 2, aK = (tid & 3) * 4;
  int bK = tid >> 4, bN = (tid & 15) * 4;
  double acc[8][4] = {};
  for (int k0 = 0; k0 < K; k0 += 16) {
    #pragma unroll
    for (int ps = 0; ps < 2; ++ps) {
      float4 a4 = *(const float4*)&A[(size_t)(m0 + aM + ps*64) * K + k0 + aK];
      As[aK+0][aM+ps*64] = a4.x; As[aK+1][aM+ps*64] = a4.y;
      As[aK+2][aM+ps*64] = a4.z; As[aK+3][aM+ps*64] = a4.w;
    }
    float4 b4 = *(const float4*)&Bw[(size_t)(k0 + bK) * N + n0 + bN];
    *(float4*)&Bs[bK][bN] = b4;
    __syncthreads();
    #pragma unroll
    for (int k = 0; k < 16; ++k) {
      double av[8], bv[4];
      #pragma unroll
      for (int r = 0; r < 8; ++r) av[r] = (double)As[k][ty*8 + r];
      #pragma unroll
      for (int c = 0; c < 4; ++c) bv[c] = (double)Bs[k][tx*4 + c];
      #pragma unroll
      for (int r = 0; r < 8; ++r)
        #pragma unroll
        for (int c = 0; c < 4; ++c)
          acc[r][c] = fma(av[r], bv[c], acc[r][c]);
    }
    __syncthreads();
  }
  #pragma unroll
  for (int r = 0; r < 8; ++r) {
    size_t off = (size_t)(m0 + ty*8 + r) * N + n0 + tx*4;
    #pragma unroll
    for (int c = 0; c < 4; ++c) {
      double v = acc[r][c];
      if (BIAS)  v += (double)bias[n0 + tx*4 + c];
      if (RESID) v += (double)resid[off + c];
      if (RELU)  v = fmax(v, 0.0);
      Co[off + c] = (float)v;
    }
  }
}

// GEMM B: BM=BN=64, BK=16, 256 thr, 4x4 f64 micro (proven R7) — used where blocks would be few
template<int BIAS, int RELU, int RESID>
__global__ __launch_bounds__(256) void k_gemmB(const float* __restrict__ A,
    const float* __restrict__ Bw, const float* __restrict__ bias,
    const float* resid, float* Co, int M, int N, int K) {
  __shared__ __align__(16) float As[16][68];
  __shared__ __align__(16) float Bs[16][68];
  int tid = threadIdx.x;
  int n0 = blockIdx.x * 64, m0 = blockIdx.y * 64;
  int tx = tid & 15, ty = tid >> 4;
  int aM = tid >> 2, aK = (tid & 3) * 4;
  int bK = tid >> 4, bN = (tid & 15) * 4;
  double acc[4][4] = {};
  for (int k0 = 0; k0 < K; k0 += 16) {
    float4 a4 = *(const float4*)&A[(size_t)(m0 + aM) * K + k0 + aK];
    As[aK+0][aM] = a4.x; As[aK+1][aM] = a4.y; As[aK+2][aM] = a4.z; As[aK+3][aM] = a4.w;
    float4 b4 = *(const float4*)&Bw[(size_t)(k0 + bK) * N + n0 + bN];
    *(float4*)&Bs[bK][bN] = b4;
    __syncthreads();
    #pragma unroll
    for (int k = 0; k < 16; ++k) {
      double av[4], bv[4];
      #pragma unroll
      for (int r = 0; r < 4; ++r) av[r] = (double)As[k][ty*4 + r];
      #pragma unroll
      for (int c = 0; c < 4; ++c) bv[c] = (double)Bs[k][tx*4 + c];
      #pragma unroll
      for (int r = 0; r < 4; ++r)
        #pragma unroll
        for (int c = 0; c < 4; ++c)
          acc[r][c] = fma(av[r], bv[c], acc[r][c]);
    }
    __syncthreads();
  }
  #pragma unroll
  for (int r = 0; r < 4; ++r) {
    size_t off = (size_t)(m0 + ty*4 + r) * N + n0 + tx*4;
    #pragma unroll
    for (int c = 0; c < 4; ++c) {
      double v = acc[r][c];
      if (BIAS)  v += (double)bias[n0 + tx*4 + c];
      if (RESID) v += (double)resid[off + c];
      if (RELU)  v = fmax(v, 0.0);
      Co[off + c] = (float)v;
    }
  }
}

// attention: f64 logits/softmax/PV
__global__ __launch_bounds__(64) void k_attn(float* __restrict__ q,
    const float* __restrict__ kb, const float* __restrict__ vb) {
  int b = blockIdx.x / NN, n = blockIdx.x % NN;
  int t = threadIdx.x;
  __shared__ float qs[256];
  __shared__ double lg[4][52];
  __shared__ double sinv[4];
  float* qrow = q + ((size_t)b*NN + n)*CC;
  #pragma unroll
  for (int i = 0; i < 4; ++i) qs[t + i*64] = qrow[t + i*64];
  __syncthreads();
  for (int li = t; li < 196; li += 64) {
    int h = li / 49, m = li % 49;
    const float* kr = kb + (((size_t)b*NHEADS + h)*49 + m)*DH;
    const float* qh = qs + h*DH;
    double acc = 0.0;
    #pragma unroll 16
    for (int d = 0; d < DH; ++d) acc = fma((double)qh[d], (double)kr[d], acc);
    lg[h][m] = acc * 0.125;
  }
  __syncthreads();
  if (t < 4) {
    double mx = -1e300;
    for (int j = 0; j < 49; ++j) mx = fmax(mx, lg[t][j]);
    double s = 0.0;
    for (int j = 0; j < 49; ++j) { double e = exp(lg[t][j] - mx); lg[t][j] = e; s += e; }
    sinv[t] = 1.0 / s;
  }
  __syncthreads();
  #pragma unroll
  for (int h = 0; h < 4; ++h) {
    const float* vr = vb + (((size_t)b*NHEADS + h)*49)*DH + t;
    double acc = 0.0;
    for (int m = 0; m < 49; ++m) acc = fma(lg[h][m], (double)vr[m*DH], acc);
    qrow[h*64 + t] = (float)(acc * sinv[h]);
  }
}

// depthwise 3x3 + bias + gelu, f64
__global__ __launch_bounds__(256) void k_dw(const float* __restrict__ hb,
    const float* __restrict__ w, const float* __restrict__ bias, float* __restrict__ h2) {
  int bl = blockIdx.x / NN, n = blockIdx.x % NN;
  int r = n / HW, c = n % HW;
  int t = threadIdx.x;
  const size_t base = (size_t)bl * NN;
  #pragma unroll
  for (int it = 0; it < 4; ++it) {
    int mc = t + it*256;
    double acc = (double)bias[mc];
    #pragma unroll
    for (int ky = 0; ky < 3; ++ky) {
      int rr = r + ky - 1;
      if (rr < 0 || rr >= HW) continue;
      #pragma unroll
      for (int kx = 0; kx < 3; ++kx) {
        int cc2 = c + kx - 1;
        if (cc2 < 0 || cc2 >= HW) continue;
        acc = fma((double)w[mc*9 + ky*3 + kx], (double)hb[(base + rr*HW + cc2)*MLPH + mc], acc);
      }
    }
    h2[(base + n)*MLPH + mc] = (float)gelu_d(acc);
  }
}

// conf scores: one wave per row, f64 dot + gumbel -> scd (global)
__global__ __launch_bounds__(256) void k_conf(const float* __restrict__ x3,
    const float* __restrict__ cw, const float* __restrict__ cb, double* __restrict__ scd) {
  int wid = (blockIdx.x * 256 + threadIdx.x) >> 6;
  int lane = threadIdx.x & 63;
  if (wid >= BB * NREST) return;
  int b = wid / NREST, i = wid % NREST;
  const float* xr = x3 + ((size_t)b*NN + NGRID + i)*CC;
  double acc = 0.0;
  #pragma unroll
  for (int r = 0; r < 4; ++r)
    acc += (double)xr[lane + r*64] * (double)cw[lane + r*64];
  #pragma unroll
  for (int o = 32; o; o >>= 1) acc += __shfl_xor(acc, o, 64);
  if (lane == 0) scd[wid] = acc + (double)cb[0] + gumbel_d(wid);
}

// exact top-k by rank counting; 6 blocks/batch, scores in LDS (broadcast reads)
__global__ __launch_bounds__(512) void k_topk2(const double* __restrict__ scd, int* __restrict__ sel) {
  int b = blockIdx.x / 6, chunk = blockIdx.x % 6;
  __shared__ double sc[NREST];
  const double* s = scd + (size_t)b * NREST;
  for (int j = threadIdx.x; j < NREST; j += 512) sc[j] = s[j];
  __syncthreads();
  int i = chunk * 512 + threadIdx.x;
  if (i < NREST) {
    double si = sc[i];
    int rank = 0;
    #pragma unroll 8
    for (int j = 0; j < NREST; ++j) {
      double sj = sc[j];
      rank += (int)((sj > si) | ((sj == si) & (j < i)));
    }
    if (rank < KADA) sel[b*KADA + rank] = NGRID + i;
  }
}

// token2map == 2x2 avg pool
__global__ __launch_bounds__(256) void k_t2m(const float* __restrict__ x3, float* __restrict__ fm) {
  int b = blockIdx.x / 784, pix = blockIdx.x % 784;
  int py = pix / 28, px = pix % 28;
  int t = threadIdx.x;
  float s = 0.f;
  #pragma unroll
  for (int dy = 0; dy < 2; ++dy)
    #pragma unroll
    for (int dx = 0; dx < 2; ++dx) {
      int p = (2*py + dy)*HW + 2*px + dx;
      s += x3[((size_t)b*NN + inv_order(p))*CC + t];
    }
  fm[((size_t)b*784 + pix)*CC + t] = s * (1.0f / 4.000001f);
}

// gather + bilinear sample + output (+KAT sentinel)
__global__ __launch_bounds__(256) void k_out(const float* __restrict__ x3,
    const float* __restrict__ fm, const int* __restrict__ sel,
    const int* __restrict__ ord, float* __restrict__ out) {
  int b = blockIdx.x / 784, slot = blockIdx.x % 784;
  int t = threadIdx.x;
  int n = (slot < NGRID) ? slot : sel[b*KADA + slot - NGRID];
  int p = ord[n];
  int r = p / HW, c = p % HW;
  int ix0 = (c - 1) >> 1;
  int iy0 = (r - 1) >> 1;
  float wx = (c & 1) ? 0.25f : 0.75f;
  float wy = (r & 1) ? 0.25f : 0.75f;
  const float* fb = fm + (size_t)b*784*CC + t;
  float v = 0.f;
  float w00 = (1.f-wx)*(1.f-wy), w01 = wx*(1.f-wy), w10 = (1.f-wx)*wy, w11 = wx*wy;
  if (ix0 >= 0   && iy0 >= 0)   v += w00 * fb[(iy0*28 + ix0)*CC];
  if (ix0+1 < 28 && iy0 >= 0)   v += w01 * fb[(iy0*28 + ix0+1)*CC];
  if (ix0 >= 0   && iy0+1 < 28) v += w10 * fb[((iy0+1)*28 + ix0)*CC];
  if (ix0+1 < 28 && iy0+1 < 28) v += w11 * fb[((iy0+1)*28 + ix0+1)*CC];
  float res = x3[((size_t)b*NN + n)*CC + t] + v;
  if (blockIdx.x == 0 && t == 0) {
    if (!tf_kat()) res += 1000.0f;
  }
  out[((size_t)b*784 + slot)*CC + t] = res;
}

// ---------- launch ----------
extern "C" void kernel_launch(void* const* d_in, const int* in_sizes, int n_in,
                              void* d_out, int out_size, void* d_ws, size_t ws_size,
                              hipStream_t stream) {
  const float* x      = (const float*)d_in[0];
  const float* ln1_g  = (const float*)d_in[1];
  const float* ln1_b  = (const float*)d_in[2];
  const float* wq     = (const float*)d_in[3];
  const float* wkv    = (const float*)d_in[4];
  const float* wproj  = (const float*)d_in[5];
  const float* bproj  = (const float*)d_in[6];
  const float* sr_w   = (const float*)d_in[7];
  const float* sr_b   = (const float*)d_in[8];
  const float* srn_g  = (const float*)d_in[9];
  const float* srn_b  = (const float*)d_in[10];
  const float* ln2_g  = (const float*)d_in[11];
  const float* ln2_b  = (const float*)d_in[12];
  const float* fc1_w  = (const float*)d_in[13];
  const float* fc1_b  = (const float*)d_in[14];
  const float* dw_w   = (const float*)d_in[15];
  const float* dw_b   = (const float*)d_in[16];
  const float* fc2_w  = (const float*)d_in[17];
  const float* fc2_b  = (const float*)d_in[18];
  const float* conf_w = (const float*)d_in[19];
  const float* conf_b = (const float*)d_in[20];
  float* out = (float*)d_out;

  float* ws = (float*)d_ws;
  const size_t SZ_XN = (size_t)BB*NN*CC;
  const size_t SZ_H  = (size_t)BCH*NN*MLPH;
  float* x_r   = ws;
  float* xn    = x_r + SZ_XN;
  float* qbuf  = xn + SZ_XN;
  float* hb    = qbuf + SZ_XN;
  float* h2b   = hb + SZ_H;
  float* srout = h2b + SZ_H;
  float* kb    = srout + (size_t)BB*49*CC;
  float* vb    = kb + (size_t)BB*NHEADS*49*DH;
  float* fm    = vb + (size_t)BB*NHEADS*49*DH;
  double* scd  = (double*)(fm + (size_t)BB*784*CC);
  int*   sel   = (int*)(scd + (size_t)BB*NREST);
  int*   ord   = sel + BB*KADA;

  k_order<<<(NN+255)/256, 256, 0, stream>>>(ord);
  k_ln1<<<BB*NN, 256, 0, stream>>>(x, ln1_g, ln1_b, x_r, xn);
  k_sr<<<BB*49, 256, 0, stream>>>(xn, sr_w, sr_b, srout);
  k_kv<<<BB*49, 256, 0, stream>>>(srout, srn_g, srn_b, wkv, kb, vb);
  k_gemmA<0,0,0><<<dim3(CC/64, BB*NN/128), 256, 0, stream>>>(xn, wq, nullptr, nullptr, qbuf, BB*NN, CC, CC);
  k_attn<<<BB*NN, 64, 0, stream>>>(qbuf, kb, vb);
  k_gemmA<1,0,1><<<dim3(CC/64, BB*NN/128), 256, 0, stream>>>(qbuf, wproj, bproj, x_r, x_r, BB*NN, CC, CC);
  k_ln2<<<BB*NN, 256, 0, stream>>>(x_r, ln2_g, ln2_b, xn);
  for (int bc = 0; bc < BB/BCH; ++bc) {
    const size_t ro = (size_t)bc * BCH * NN;
    k_gemmA<1,1,0><<<dim3(MLPH/64, BCH*NN/128), 256, 0, stream>>>(xn + ro*CC, fc1_w, fc1_b, nullptr, hb, BCH*NN, MLPH, CC);
    k_dw<<<BCH*NN, 256, 0, stream>>>(hb, dw_w, dw_b, h2b);
    k_gemmB<1,0,1><<<dim3(CC/64, BCH*NN/64), 256, 0, stream>>>(h2b, fc2_w, fc2_b, x_r + ro*CC, x_r + ro*CC, BCH*NN, CC, MLPH);
  }
  k_conf<<<(BB*NREST*64 + 255)/256, 256, 0, stream>>>(x_r, conf_w, conf_b, scd);
  k_topk2<<<BB*6, 512, 0, stream>>>(scd, sel);
  k_t2m<<<BB*784, 256, 0, stream>>>(x_r, fm);
  k_out<<<BB*784, 256, 0, stream>>>(x_r, fm, sel, ord, out);
}